// Round 5
// baseline (42.667 us; speedup 1.0000x reference)
//
#include <hip/hip_runtime.h>

// Problem constants (from reference): feat (32, 64, 112, 112) fp32
#define BB 32
#define CC 64
#define HH 112
#define WW 112
#define HW (HH * WW)          // 12544
#define KS 14
#define HP (HH - KS + 1)      // 99
#define WP (WW - KS + 1)      // 99

#define BR 11                 // pooled rows per band
#define NB 9                  // 9 * 11 = 99 = HP exactly

// Kernel 1: s2[b,h,w] = (sum_c feat[b,c,h,w])^2, float4-vectorized over (h,w).
// EXACT R3 version. Launched TWICE this round as a timing ablation:
// chan_time = total_R5 - total_R3 - launch_overhead.
__global__ __launch_bounds__(256) void chan_sum_sq(const float* __restrict__ feat,
                                                   float* __restrict__ s2) {
    const int n4 = BB * (HW / 4);
    int idx4 = blockIdx.x * blockDim.x + threadIdx.x;
    if (idx4 >= n4) return;
    int b = idx4 / (HW / 4);
    int r = idx4 % (HW / 4);
    const float4* base =
        reinterpret_cast<const float4*>(feat) + (size_t)b * CC * (HW / 4) + r;
    float4 acc = make_float4(0.f, 0.f, 0.f, 0.f);
#pragma unroll 16
    for (int c = 0; c < CC; ++c) {
        float4 v = base[(size_t)c * (HW / 4)];
        acc.x += v.x; acc.y += v.y; acc.z += v.z; acc.w += v.w;
    }
    float4 o;
    o.x = acc.x * acc.x;
    o.y = acc.y * acc.y;
    o.z = acc.z * acc.z;
    o.w = acc.w * acc.w;
    reinterpret_cast<float4*>(s2)[idx4] = o;
}

// Kernel 2: band-tiled fused pooling + sim (unchanged from R3).
__global__ __launch_bounds__(256) void pool_sim_band(const float* __restrict__ s2,
                                                     float* __restrict__ out) {
    __shared__ float hbuf[(BR + 2 + KS - 1) * WP];  // up to 26 rows of h-sums
    __shared__ float pbuf[(BR + 2) * WP];           // up to 13 rows of pooled

    const int b = blockIdx.y;
    const int band = blockIdx.x;
    const int r0 = band * BR;
    const int rend = min(r0 + BR, HP);
    const int pstart = max(r0 - 1, 0);
    const int pend = min(r0 + BR + 1, HP);
    const int pcount = pend - pstart;
    const int hcount = pcount + KS - 1;
    const int tid = threadIdx.x;
    const float* img = s2 + (size_t)b * HW;

    // Horizontal 14-tap sums for rows [pstart, pstart+hcount)
    for (int i = tid; i < hcount * WP; i += 256) {
        int hr = i / WP;
        int wp = i - hr * WP;
        const float* row = img + (pstart + hr) * WW + wp;
        float s = 0.f;
#pragma unroll
        for (int k = 0; k < KS; ++k) s += row[k];
        hbuf[i] = s;
    }
    __syncthreads();

    // Vertical 14-tap sums * 1/196 for pooled rows [pstart, pend)
    for (int i = tid; i < pcount * WP; i += 256) {
        int pr = i / WP;
        int wp = i - pr * WP;
        const float* col = hbuf + pr * WP + wp;
        float s = 0.f;
#pragma unroll
        for (int k = 0; k < KS; ++k) s += col[k * WP];
        pbuf[i] = s * (1.f / (float)(KS * KS));
    }
    __syncthreads();

    // Sim: out = C^2 * center * (zero-padded 8-neighbor sum), rows [r0, rend)
    float* ob = out + (size_t)b * HP * WP;
    for (int i = tid; i < (rend - r0) * WP; i += 256) {
        int rr = i / WP;
        int wp = i - rr * WP;
        int hp = r0 + rr;
        float center = pbuf[(hp - pstart) * WP + wp];
        float ns = 0.f;
#pragma unroll
        for (int dy = -1; dy <= 1; ++dy) {
#pragma unroll
            for (int dx = -1; dx <= 1; ++dx) {
                if (dy == 0 && dx == 0) continue;
                int y = hp + dy, x = wp + dx;
                if (y >= 0 && y < HP && x >= 0 && x < WP) {
                    ns += pbuf[(y - pstart) * WP + x];
                }
            }
        }
        ob[hp * WP + wp] = (float)(CC * CC) * center * ns;
    }
}

extern "C" void kernel_launch(void* const* d_in, const int* in_sizes, int n_in,
                              void* d_out, int out_size, void* d_ws, size_t ws_size,
                              hipStream_t stream) {
    const float* feat = (const float*)d_in[0];
    float* out = (float*)d_out;
    float* s2 = (float*)d_ws;  // BB*HW = 401,408 floats = 1.6 MB

    int n4 = BB * (HW / 4);
    int blk = 256;
    // ABLATION: launch chan_sum_sq twice (idempotent). Second launch's time
    // isolates chan cost: chan = total_R5 - total_R3 - ~0.9us launch overhead.
    chan_sum_sq<<<(n4 + blk - 1) / blk, blk, 0, stream>>>(feat, s2);
    chan_sum_sq<<<(n4 + blk - 1) / blk, blk, 0, stream>>>(feat, s2);
    {
        dim3 grid(NB, BB);
        pool_sim_band<<<grid, 256, 0, stream>>>(s2, out);
    }
}

// Round 6
// 27.712 us; speedup vs baseline: 1.5397x; 1.5397x over previous
//
#include <hip/hip_runtime.h>

// Problem constants (from reference): feat (32, 64, 112, 112) fp32
#define BB 32
#define CC 64
#define HH 112
#define WW 112
#define HW (HH * WW)          // 12544
#define KS 14
#define HP (HH - KS + 1)      // 99
#define WP (WW - KS + 1)      // 99

#define BR 11                 // pooled rows per band
#define NB 9                  // 9 * 11 = 99 = HP exactly
#define MAXH 26               // max staged rows: (BR+2) pooled + 13 halo

// Kernel 1: s2[b,h,w] = (sum_c feat[b,c,h,w])^2, float4-vectorized.
// Measured at 15.3 us (R5 ablation) = ~6.7 TB/s -> at HBM roofline. Unchanged.
__global__ __launch_bounds__(256) void chan_sum_sq(const float* __restrict__ feat,
                                                   float* __restrict__ s2) {
    const int n4 = BB * (HW / 4);
    int idx4 = blockIdx.x * blockDim.x + threadIdx.x;
    if (idx4 >= n4) return;
    int b = idx4 / (HW / 4);
    int r = idx4 % (HW / 4);
    const float4* base =
        reinterpret_cast<const float4*>(feat) + (size_t)b * CC * (HW / 4) + r;
    float4 acc = make_float4(0.f, 0.f, 0.f, 0.f);
#pragma unroll 16
    for (int c = 0; c < CC; ++c) {
        float4 v = base[(size_t)c * (HW / 4)];
        acc.x += v.x; acc.y += v.y; acc.z += v.z; acc.w += v.w;
    }
    float4 o;
    o.x = acc.x * acc.x;
    o.y = acc.y * acc.y;
    o.z = acc.z * acc.z;
    o.w = acc.w * acc.w;
    reinterpret_cast<float4*>(s2)[idx4] = o;
}

// Kernel 2 v2: band-tiled pooling + sim, with s2 rows STAGED IN LDS via float4.
// R5 ablation showed v1 cost ~12us: 36K scalar global loads/block (VMEM-issue
// bound). v2 stages 26 rows (728 float4 loads/block) then h-sums read LDS.
__global__ __launch_bounds__(256) void pool_sim_band(const float* __restrict__ s2,
                                                     float* __restrict__ out) {
    __shared__ float srow[MAXH][WW];      // staged s2 rows   (11.6 KB)
    __shared__ float hbuf[MAXH * WP];     // horizontal sums  (10.3 KB)
    __shared__ float pbuf[(BR + 2) * WP]; // pooled rows      ( 5.1 KB)

    const int b = blockIdx.y;
    const int band = blockIdx.x;
    const int r0 = band * BR;
    const int rend = min(r0 + BR, HP);
    const int pstart = max(r0 - 1, 0);
    const int pend = min(r0 + BR + 1, HP);
    const int pcount = pend - pstart;
    const int hcount = pcount + KS - 1;   // <= 26 rows of s2 needed
    const int tid = threadIdx.x;

    // Stage s2 rows [pstart, pstart+hcount) into LDS with float4 loads.
    // Rows are 112 floats = 28 float4, 16B-aligned (112 % 4 == 0).
    const float4* img4 = reinterpret_cast<const float4*>(s2 + (size_t)b * HW);
    for (int i = tid; i < hcount * (WW / 4); i += 256) {
        int hr = i / (WW / 4);
        int c4 = i - hr * (WW / 4);
        reinterpret_cast<float4*>(&srow[hr][0])[c4] = img4[(pstart + hr) * (WW / 4) + c4];
    }
    __syncthreads();

    // Horizontal 14-tap sums from LDS.
    for (int i = tid; i < hcount * WP; i += 256) {
        int hr = i / WP;
        int wp = i - hr * WP;
        float s = 0.f;
#pragma unroll
        for (int k = 0; k < KS; ++k) s += srow[hr][wp + k];
        hbuf[i] = s;
    }
    __syncthreads();

    // Vertical 14-tap sums * 1/196 for pooled rows [pstart, pend)
    for (int i = tid; i < pcount * WP; i += 256) {
        int pr = i / WP;
        int wp = i - pr * WP;
        const float* col = hbuf + pr * WP + wp;
        float s = 0.f;
#pragma unroll
        for (int k = 0; k < KS; ++k) s += col[k * WP];
        pbuf[i] = s * (1.f / (float)(KS * KS));
    }
    __syncthreads();

    // Sim: out = C^2 * center * (zero-padded 8-neighbor sum), rows [r0, rend)
    float* ob = out + (size_t)b * HP * WP;
    for (int i = tid; i < (rend - r0) * WP; i += 256) {
        int rr = i / WP;
        int wp = i - rr * WP;
        int hp = r0 + rr;
        float center = pbuf[(hp - pstart) * WP + wp];
        float ns = 0.f;
#pragma unroll
        for (int dy = -1; dy <= 1; ++dy) {
#pragma unroll
            for (int dx = -1; dx <= 1; ++dx) {
                if (dy == 0 && dx == 0) continue;
                int y = hp + dy, x = wp + dx;
                if (y >= 0 && y < HP && x >= 0 && x < WP) {
                    ns += pbuf[(y - pstart) * WP + x];
                }
            }
        }
        ob[hp * WP + wp] = (float)(CC * CC) * center * ns;
    }
}

extern "C" void kernel_launch(void* const* d_in, const int* in_sizes, int n_in,
                              void* d_out, int out_size, void* d_ws, size_t ws_size,
                              hipStream_t stream) {
    const float* feat = (const float*)d_in[0];
    float* out = (float*)d_out;
    float* s2 = (float*)d_ws;  // BB*HW = 401,408 floats = 1.6 MB

    {
        int n4 = BB * (HW / 4);
        int blk = 256;
        chan_sum_sq<<<(n4 + blk - 1) / blk, blk, 0, stream>>>(feat, s2);
    }
    {
        dim3 grid(NB, BB);
        pool_sim_band<<<grid, 256, 0, stream>>>(s2, out);
    }
}